// Round 8
// baseline (282.337 us; speedup 1.0000x reference)
//
#include <hip/hip_runtime.h>
#include <math.h>

// Problem constants
#define B_   16
#define T_   64
#define N_   22
#define D_   64
#define K_   4
#define E_   8
#define H_   64
#define TW   59                 // valid time steps per batch (t=2..60 absolute)
#define M_   (B_ * TW)          // 944
#define NE_  (N_ * E_)          // 176
#define NDXT (N_ * D_)          // 1408
#define XTOT (B_ * T_ * N_ * D_)   // 1,441,792

typedef __attribute__((ext_vector_type(8))) short short8;
typedef __attribute__((ext_vector_type(4))) float float4v;

union Frag {
    short8 s8;
    unsigned u[4];
};

// workspace layout
#define ERRWS_BYTES  ((size_t)(M_ * N_ * E_) * 4)          // 664,576
#define XH_OFF       (ERRWS_BYTES)
#define XIMG_BYTES   ((size_t)XTOT * 2)                    // 2,883,584
#define XL_OFF       (XH_OFF + XIMG_BYTES)

#define HIMG_ROW 68        // dwords per h-image row (64 + 4 pad)

// trunc-split: hi = trunc bf16, lo = trunc bf16 of residual.
__device__ inline void split2(float f, unsigned& hi, unsigned& lo) {
    unsigned u  = __float_as_uint(f);
    unsigned ht = u & 0xffff0000u;
    float rem   = f - __uint_as_float(ht);
    hi = u >> 16;
    lo = __float_as_uint(rem) >> 16;
}

// ---------------------------------------------------------------------------
// Precompute: x -> bf16 hi/lo images (same linear layout as x). ~17 MB traffic.
__global__ __launch_bounds__(256) void xsplit_kernel(
    const float* __restrict__ x, short* __restrict__ xh, short* __restrict__ xl)
{
    int i = (blockIdx.x * 256 + threadIdx.x) * 4;
    if (i >= XTOT) return;
    float4 v = *(const float4*)(x + i);
    unsigned h0, h1, h2, h3, l0, l1, l2, l3;
    split2(v.x, h0, l0); split2(v.y, h1, l1);
    split2(v.z, h2, l2); split2(v.w, h3, l3);
    uint2 hp, lp;
    hp.x = h0 | (h1 << 16); hp.y = h2 | (h3 << 16);
    lp.x = l0 | (l1 << 16); lp.y = l2 | (l3 << 16);
    *(uint2*)(xh + i) = hp;
    *(uint2*)(xl + i) = lp;
}

// ---------------------------------------------------------------------------
// Main kernel. Block = (n, e, mtile of 128 rows); swizzle g = mt + 8*e + 64*n
// -> XCD = mt: each XCD owns a 128-row m-slice whose x-images (~1.1 MB) stay
// L2-resident (R7 lesson: XCD=e thrashed L2 with the full 5.8 MB x-image).
// W streams from L3 with a 2-chunk-ahead register prefetch (wf dbuf).
// 4 waves, each 32 rows x 64 cols. Hygiene: no runtime-indexed local arrays.
__global__ __launch_bounds__(256, 3) void moe_err_kernel(
    const float* __restrict__ x, const short* __restrict__ xh,
    const short* __restrict__ xl, const int* __restrict__ nb,
    const float* __restrict__ W1, const float* __restrict__ W2,
    const float* __restrict__ W3,
    const float* __restrict__ b1, const float* __restrict__ b2,
    const float* __restrict__ b3, float* __restrict__ err_ws)
{
    const int tid = threadIdx.x;
    const int w   = tid >> 6;
    const int L   = tid & 63;
    const int g   = blockIdx.x;
    const int mt  = g & 7;            // XCD = mt
    const int e   = (g >> 3) & 7;
    const int n   = g >> 6;
    const int ne  = n * E_ + e;

    __shared__ __align__(16) char smem[51200];     // 3 blocks/CU
    unsigned char* wbuf = (unsigned char*)smem;    // 16 KB: 16 W images x 1 KB
    unsigned* himg = (unsigned*)(smem + 16384);    // 34,816 B: 128 x 68 dwords

    const int lrow = L & 15;           // A row within 16
    const int dseg = (L >> 4) * 8;     // k-subsegment
    const int ccol = L & 15;           // C col within 16-group
    const int qrow = (L >> 4) * 4;     // C row quad base
    const int rowbase = mt * 128 + w * 32;

    // per-rowtile lane row -> base into x images
    const short* xhrow[2];
    const short* xlrow[2];
    #pragma unroll
    for (int rt = 0; rt < 2; ++rt) {
        int m  = rowbase + rt * 16 + lrow;
        int mc = m < M_ ? m : M_ - 1;
        int b = mc / TW, t = mc % TW;
        size_t base = (size_t)(b * T_ + t) * NDXT;
        xhrow[rt] = xh + base;
        xlrow[rt] = xl + base;
    }

    // neighbor offsets (wave-uniform scalars)
    const int o0 = __builtin_amdgcn_readfirstlane(nb[n * K_ + 0]) * D_;
    const int o1 = __builtin_amdgcn_readfirstlane(nb[n * K_ + 1]) * D_;
    const int o2 = __builtin_amdgcn_readfirstlane(nb[n * K_ + 2]) * D_;
    const int o3 = __builtin_amdgcn_readfirstlane(nb[n * K_ + 3]) * D_;

    const float* W1ne = W1 + (size_t)ne * (1280 * 64);
    const float* W2ne = W2 + (size_t)ne * 4096;
    const float* W3ne = W3 + (size_t)ne * 4096;
    auto csrc = [&](int c) {
        return c < 20 ? (W1ne + (size_t)c * 4096) : (c == 20 ? W2ne : W3ne);
    };

    // ---- W pipeline: fp32 strided load (2 chunks ahead, wf dbuf) ->
    // trunc-split -> packed regs -> LDS images. Wave w owns pairs 2w, 2w+1.
    float wf[2][2][8];                 // [buf][pair][j]
    uint4 wph[2], wpl[2];
    auto loadWf = [&](int wb, const float* src) {
        #pragma unroll
        for (int p = 0; p < 2; ++p) {
            const int pi = 2 * w + p;
            const float* sp = src + ((pi >> 2) * 32 + (L >> 4) * 8) * 64
                                  + ((pi & 3) * 16 + (L & 15));
            #pragma unroll
            for (int j = 0; j < 8; ++j) wf[wb][p][j] = sp[j * 64];
        }
    };
    auto packW = [&](int wb) {
        #pragma unroll
        for (int p = 0; p < 2; ++p) {
            unsigned hs[8], ls[8];
            #pragma unroll
            for (int j = 0; j < 8; ++j) split2(wf[wb][p][j], hs[j], ls[j]);
            wph[p].x = hs[0] | (hs[1] << 16); wph[p].y = hs[2] | (hs[3] << 16);
            wph[p].z = hs[4] | (hs[5] << 16); wph[p].w = hs[6] | (hs[7] << 16);
            wpl[p].x = ls[0] | (ls[1] << 16); wpl[p].y = ls[2] | (ls[3] << 16);
            wpl[p].z = ls[4] | (ls[5] << 16); wpl[p].w = ls[6] | (ls[7] << 16);
        }
    };
    auto storeW = [&]() {
        #pragma unroll
        for (int p = 0; p < 2; ++p) {
            char* bp = (char*)wbuf + (size_t)(2 * w + p) * 2048 + (size_t)L * 16;
            *(uint4*)bp          = wph[p];
            *(uint4*)(bp + 1024) = wpl[p];
        }
    };
    auto bfrag = [&](int s2, int cf, int hl) -> short8 {
        return *(const short8*)(wbuf + (size_t)((s2 * 4 + cf) * 2 + hl) * 1024
                                     + (size_t)L * 16);
    };

    // prologue: chunk0 -> wf0, chunk1 -> wf1; pack chunk0
    loadWf(0, csrc(0));
    loadWf(1, csrc(1));
    packW(0);

    float4v acc1[2][4];
    #pragma unroll
    for (int rt = 0; rt < 2; ++rt)
        #pragma unroll
        for (int cf = 0; cf < 4; ++cf) acc1[rt][cf] = (float4v)0.f;

    // ---------------- GEMM1: 20 chunks of K=64 ----------------
    for (int dt = 0; dt < 5; ++dt) {
        #pragma unroll
        for (int kk = 0; kk < 4; ++kk) {
            const int c = dt * 4 + kk;
            __syncthreads();          // prev chunk's B-reads done
            storeW();                 // chunk c images (packed last iter)
            __syncthreads();          // images visible

            loadWf(c & 1, csrc(c + 2 <= 21 ? c + 2 : 21));  // wf[c&1] free: c+2

            const int okk = (kk == 0) ? o0 : ((kk == 1) ? o1 : ((kk == 2) ? o2 : o3));
            const int off = dt * NDXT + okk;

            Frag ah[2][2], al[2][2];  // [s2][rt]
            #pragma unroll
            for (int s2 = 0; s2 < 2; ++s2)
                #pragma unroll
                for (int rt = 0; rt < 2; ++rt) {
                    ah[s2][rt].s8 = *(const short8*)(xhrow[rt] + off + s2 * 32 + dseg);
                    al[s2][rt].s8 = *(const short8*)(xlrow[rt] + off + s2 * 32 + dseg);
                }
            #pragma unroll
            for (int s2 = 0; s2 < 2; ++s2)
                #pragma unroll
                for (int cf = 0; cf < 4; ++cf) {
                    short8 bh = bfrag(s2, cf, 0);
                    short8 bl = bfrag(s2, cf, 1);
                    #pragma unroll
                    for (int rt = 0; rt < 2; ++rt) {
                        acc1[rt][cf] = __builtin_amdgcn_mfma_f32_16x16x32_bf16(ah[s2][rt].s8, bh, acc1[rt][cf], 0, 0, 0);
                        acc1[rt][cf] = __builtin_amdgcn_mfma_f32_16x16x32_bf16(ah[s2][rt].s8, bl, acc1[rt][cf], 0, 0, 0);
                        acc1[rt][cf] = __builtin_amdgcn_mfma_f32_16x16x32_bf16(al[s2][rt].s8, bh, acc1[rt][cf], 0, 0, 0);
                    }
                }
            packW((c + 1) & 1);       // pack chunk c+1 (loads issued at c-1: covered)
        }
    }

    // ---------------- h1 = relu(acc1 + b1) -> packed h-image; stage W2 ------
    __syncthreads();                  // chunk19 B-reads done
    storeW();                         // W2 images (chunk20, packed at c=19)
    #pragma unroll
    for (int cf = 0; cf < 4; ++cf) {
        float bv = b1[(size_t)ne * H_ + cf * 16 + ccol];
        #pragma unroll
        for (int rt = 0; rt < 2; ++rt)
            #pragma unroll
            for (int reg = 0; reg < 4; ++reg) {
                float hv = fmaxf(acc1[rt][cf][reg] + bv, 0.f);
                unsigned u  = __float_as_uint(hv);
                unsigned ht = u & 0xffff0000u;
                float rem   = hv - __uint_as_float(ht);
                himg[(w * 32 + rt * 16 + qrow + reg) * HIMG_ROW + cf * 16 + ccol] =
                    ht | (__float_as_uint(rem) >> 16);      // wave-private rows
            }
    }
    packW(1);                         // pack W3 (chunk21, loaded at c=19)
    __syncthreads();                  // W2 images visible (+ own h1 rows)

    // ---------------- GEMM2: h1 @ W2 (K=64) ----------------
    float4v acc2[2][4];
    #pragma unroll
    for (int rt = 0; rt < 2; ++rt)
        #pragma unroll
        for (int cf = 0; cf < 4; ++cf) acc2[rt][cf] = (float4v)0.f;
    #pragma unroll
    for (int s2 = 0; s2 < 2; ++s2) {
        Frag ah[2], al[2];
        #pragma unroll
        for (int rt = 0; rt < 2; ++rt) {
            const unsigned* hp = himg + (w * 32 + rt * 16 + lrow) * HIMG_ROW + s2 * 32 + dseg;
            uint4 u0 = *(const uint4*)hp;
            uint4 u1 = *(const uint4*)(hp + 4);
            unsigned uu[8] = {u0.x, u0.y, u0.z, u0.w, u1.x, u1.y, u1.z, u1.w};
            #pragma unroll
            for (int i = 0; i < 4; ++i) {
                ah[rt].u[i] = (uu[2 * i] >> 16) | (uu[2 * i + 1] & 0xffff0000u);
                al[rt].u[i] = (uu[2 * i] & 0xffffu) | (uu[2 * i + 1] << 16);
            }
        }
        #pragma unroll
        for (int cf = 0; cf < 4; ++cf) {
            short8 bh = bfrag(s2, cf, 0);
            short8 bl = bfrag(s2, cf, 1);
            #pragma unroll
            for (int rt = 0; rt < 2; ++rt) {
                acc2[rt][cf] = __builtin_amdgcn_mfma_f32_16x16x32_bf16(ah[rt].s8, bh, acc2[rt][cf], 0, 0, 0);
                acc2[rt][cf] = __builtin_amdgcn_mfma_f32_16x16x32_bf16(ah[rt].s8, bl, acc2[rt][cf], 0, 0, 0);
                acc2[rt][cf] = __builtin_amdgcn_mfma_f32_16x16x32_bf16(al[rt].s8, bh, acc2[rt][cf], 0, 0, 0);
            }
        }
    }

    // ---------------- h2 = relu(acc2 + b2) -> h-image; stage W3 -------------
    __syncthreads();                  // W2 image + h1 reads done
    storeW();                         // W3 images
    #pragma unroll
    for (int cf = 0; cf < 4; ++cf) {
        float bv = b2[(size_t)ne * H_ + cf * 16 + ccol];
        #pragma unroll
        for (int rt = 0; rt < 2; ++rt)
            #pragma unroll
            for (int reg = 0; reg < 4; ++reg) {
                float hv = fmaxf(acc2[rt][cf][reg] + bv, 0.f);
                unsigned u  = __float_as_uint(hv);
                unsigned ht = u & 0xffff0000u;
                float rem   = hv - __uint_as_float(ht);
                himg[(w * 32 + rt * 16 + qrow + reg) * HIMG_ROW + cf * 16 + ccol] =
                    ht | (__float_as_uint(rem) >> 16);
            }
    }
    __syncthreads();                  // W3 images + h2 visible

    // ---------------- GEMM3: h2 @ W3 -> pred; err epilogue ------------------
    float4v acc3[2][4];
    #pragma unroll
    for (int rt = 0; rt < 2; ++rt)
        #pragma unroll
        for (int cf = 0; cf < 4; ++cf) acc3[rt][cf] = (float4v)0.f;
    #pragma unroll
    for (int s2 = 0; s2 < 2; ++s2) {
        Frag ah[2], al[2];
        #pragma unroll
        for (int rt = 0; rt < 2; ++rt) {
            const unsigned* hp = himg + (w * 32 + rt * 16 + lrow) * HIMG_ROW + s2 * 32 + dseg;
            uint4 u0 = *(const uint4*)hp;
            uint4 u1 = *(const uint4*)(hp + 4);
            unsigned uu[8] = {u0.x, u0.y, u0.z, u0.w, u1.x, u1.y, u1.z, u1.w};
            #pragma unroll
            for (int i = 0; i < 4; ++i) {
                ah[rt].u[i] = (uu[2 * i] >> 16) | (uu[2 * i + 1] & 0xffff0000u);
                al[rt].u[i] = (uu[2 * i] & 0xffffu) | (uu[2 * i + 1] << 16);
            }
        }
        #pragma unroll
        for (int cf = 0; cf < 4; ++cf) {
            short8 bh = bfrag(s2, cf, 0);
            short8 bl = bfrag(s2, cf, 1);
            #pragma unroll
            for (int rt = 0; rt < 2; ++rt) {
                acc3[rt][cf] = __builtin_amdgcn_mfma_f32_16x16x32_bf16(ah[rt].s8, bh, acc3[rt][cf], 0, 0, 0);
                acc3[rt][cf] = __builtin_amdgcn_mfma_f32_16x16x32_bf16(ah[rt].s8, bl, acc3[rt][cf], 0, 0, 0);
                acc3[rt][cf] = __builtin_amdgcn_mfma_f32_16x16x32_bf16(al[rt].s8, bh, acc3[rt][cf], 0, 0, 0);
            }
        }
    }

    {
        float b3v[4];
        #pragma unroll
        for (int cf = 0; cf < 4; ++cf) b3v[cf] = b3[(size_t)ne * D_ + cf * 16 + ccol];

        #pragma unroll
        for (int rt = 0; rt < 2; ++rt) {
            #pragma unroll
            for (int reg = 0; reg < 4; ++reg) {
                const int m  = rowbase + rt * 16 + qrow + reg;
                const int mc = m < M_ ? m : M_ - 1;
                const int b = mc / TW, t = mc % TW;
                const float* yp = x + ((size_t)(b * T_ + t + 2) * N_ + n) * D_;
                float s = 0.f;
                #pragma unroll
                for (int cf = 0; cf < 4; ++cf) {
                    float d = acc3[rt][cf][reg] + b3v[cf] - yp[cf * 16 + ccol];
                    s += d * d;
                }
                s += __shfl_xor(s, 1);
                s += __shfl_xor(s, 2);
                s += __shfl_xor(s, 4);
                s += __shfl_xor(s, 8);
                if (ccol == 0 && m < M_) {
                    err_ws[((size_t)m * N_ + n) * E_ + e] = s * (1.f / 64.f);
                }
            }
        }
    }
}

// ---------------------------------------------------------------------------
// Fused reduce: single block, 1024 threads. No atomics, no init kernel:
// block-internal tree reduction writes out[0] once; expert_idx written direct.
__global__ __launch_bounds__(1024) void moe_reduce_kernel(
    const float* __restrict__ err_ws, float* __restrict__ out)
{
    const int tid = threadIdx.x;
    float partial = 0.f;
    for (int idx = tid; idx < M_ * N_; idx += 1024) {
        const int m = idx / N_, n = idx % N_;
        const float* ep = err_ws + (size_t)idx * E_;
        float ev[E_];
        float4 e0 = *(const float4*)ep;
        float4 e1 = *(const float4*)(ep + 4);
        ev[0] = e0.x; ev[1] = e0.y; ev[2] = e0.z; ev[3] = e0.w;
        ev[4] = e1.x; ev[5] = e1.y; ev[6] = e1.z; ev[7] = e1.w;
        float mn = ev[0];
        int am = 0;
        #pragma unroll
        for (int i = 1; i < E_; ++i) {
            if (ev[i] < mn) { mn = ev[i]; am = i; }
        }
        float p[E_];
        float Z = 0.f;
        #pragma unroll
        for (int i = 0; i < E_; ++i) { p[i] = expf(mn - ev[i]); Z += p[i]; }
        const float invZ = 1.f / Z;
        float kl = 0.f;
        #pragma unroll
        for (int i = 0; i < E_; ++i) {
            float q = p[i] * invZ;
            kl += q * (logf(q + 1e-9f) + 2.0794415416798357f);  // log(8)
        }
        partial += mn + 0.01f * kl;
        const int t = m % TW, b = m / TW;
        if (t == TW - 1 && n == N_ - 1) out[1 + b] = (float)am;
    }
    __shared__ float sd[1024];
    sd[tid] = partial;
    __syncthreads();
    for (int s = 512; s > 0; s >>= 1) {
        if (tid < s) sd[tid] += sd[tid + s];
        __syncthreads();
    }
    if (tid == 0) out[0] = sd[0] * (1.f / 20160.f);  // / B / (N-1) / (T-4)
}

extern "C" void kernel_launch(void* const* d_in, const int* in_sizes, int n_in,
                              void* d_out, int out_size, void* d_ws, size_t ws_size,
                              hipStream_t stream)
{
    const float* x  = (const float*)d_in[0];
    const int*   nb = (const int*)d_in[1];
    const float* W1 = (const float*)d_in[2];
    const float* b1 = (const float*)d_in[3];
    const float* W2 = (const float*)d_in[4];
    const float* b2 = (const float*)d_in[5];
    const float* W3 = (const float*)d_in[6];
    const float* b3 = (const float*)d_in[7];
    float* out    = (float*)d_out;
    float* err_ws = (float*)d_ws;
    short* xh     = (short*)((char*)d_ws + XH_OFF);
    short* xl     = (short*)((char*)d_ws + XL_OFF);

    hipLaunchKernelGGL(xsplit_kernel, dim3(1408), dim3(256), 0, stream, x, xh, xl);
    hipLaunchKernelGGL(moe_err_kernel, dim3(NE_ * 8), dim3(256), 0, stream,
                       x, xh, xl, nb, W1, W2, W3, b1, b2, b3, err_ws);
    hipLaunchKernelGGL(moe_reduce_kernel, dim3(1), dim3(1024), 0, stream, err_ws, out);
}